// Round 9
// baseline (78.672 us; speedup 1.0000x reference)
//
#include <hip/hip_runtime.h>

#define SEQ 512
#define MD  1024
#define RK  128

typedef __attribute__((ext_vector_type(8))) short  bf16x8;
typedef __attribute__((ext_vector_type(4))) float  floatx4;
typedef __attribute__((ext_vector_type(4))) unsigned short ushortx4;

// RNE f32->bf16 (used only for T / norm outputs, off the hot loop)
__device__ inline unsigned short f2bf(float f) {
    union { float f; unsigned u; } v; v.f = f;
    unsigned r = v.u + 0x7fffu + ((v.u >> 16) & 1u);
    return (unsigned short)(r >> 16);
}

// Truncating pack of two f32 -> two bf16 in one v_perm_b32 (hot-loop cvt).
// result low short = hi-half of `lo`, high short = hi-half of `hi`.
__device__ inline unsigned pkbf(float lo, float hi) {
    union { float f; unsigned u; } a, b; a.f = lo; b.f = hi;
    return __builtin_amdgcn_perm(b.u, a.u, 0x07060302u);
}

#define REDW 2112   // 16 * 132 floats per wave partial (proj reduce)

// ---------- Kernel 1: T = bf16(batch @ proj) + row norms, via MFMA ----------
// 256 blocks x 512 threads (8 waves). Block owns 16 rows; wave w owns a K-eighth.
// A-frags: fp32 dwordx4 from batch. B-frags: 8 strided dword gathers from fp32
// proj (L2-resident, shared). Input cvt = v_perm truncation (1 instr / 2 elems).
__global__ __launch_bounds__(512, 2) void proj_direct(
    const float* __restrict__ batch, const float* __restrict__ proj,
    unsigned short* __restrict__ T, float* __restrict__ Nrm)
{
    __shared__ float Red[8 * REDW];   // 67.6 KB

    const int t    = threadIdx.x;
    const int w    = t >> 6;
    const int l    = t & 63;
    const int lm   = l & 15;
    const int quad = l >> 4;
    const int r0   = blockIdx.x * 16;

    floatx4 acc[8];
    #pragma unroll
    for (int i = 0; i < 8; ++i) acc[i] = (floatx4){0.f, 0.f, 0.f, 0.f};

    const float* arow = batch + (size_t)(r0 + lm) * MD + w * 128 + quad * 8;

    #pragma unroll
    for (int s = 0; s < 4; ++s) {
        // A fragment: lane holds A[m=lm][k = w*128 + s*32 + quad*8 + j]
        float4 a0 = *(const float4*)(arow + s * 32);
        float4 a1 = *(const float4*)(arow + s * 32 + 4);
        union { bf16x8 v; unsigned u[4]; } av;
        av.u[0] = pkbf(a0.x, a0.y); av.u[1] = pkbf(a0.z, a0.w);
        av.u[2] = pkbf(a1.x, a1.y); av.u[3] = pkbf(a1.z, a1.w);

        // B fragments: lane needs proj[k][n], n = nt*16+lm, k stride RK
        const float* bk = proj + (size_t)(w * 128 + s * 32 + quad * 8) * RK + lm;
        #pragma unroll
        for (int nt = 0; nt < 8; ++nt) {
            const float* bp = bk + nt * 16;
            float b0 = bp[0],      b1 = bp[RK],     b2 = bp[2 * RK], b3 = bp[3 * RK];
            float b4 = bp[4 * RK], b5 = bp[5 * RK], b6 = bp[6 * RK], b7 = bp[7 * RK];
            union { bf16x8 v; unsigned u[4]; } bv;
            bv.u[0] = pkbf(b0, b1); bv.u[1] = pkbf(b2, b3);
            bv.u[2] = pkbf(b4, b5); bv.u[3] = pkbf(b6, b7);
            acc[nt] = __builtin_amdgcn_mfma_f32_16x16x32_bf16(av.v, bv.v, acc[nt], 0, 0, 0);
        }
    }

    // dump per-wave partials; row stride 132 -> 2-way bank alias only (free)
    #pragma unroll
    for (int nt = 0; nt < 8; ++nt) {
        #pragma unroll
        for (int r = 0; r < 4; ++r) {
            Red[w * REDW + (quad * 4 + r) * 132 + nt * 16 + lm] = acc[nt][r];
        }
    }
    __syncthreads();

    // conflict-free b128 reduce: thread -> (row = t>>5, col4 = (t&31)*4)
    {
        const int row  = t >> 5;
        const int col4 = (t & 31) * 4;
        float4 s4 = {0.f, 0.f, 0.f, 0.f};
        #pragma unroll
        for (int ww = 0; ww < 8; ++ww) {
            float4 p = *(const float4*)(Red + ww * REDW + row * 132 + col4);
            s4.x += p.x; s4.y += p.y; s4.z += p.z; s4.w += p.w;
        }
        unsigned short tmp[4];
        tmp[0] = f2bf(s4.x); tmp[1] = f2bf(s4.y);
        tmp[2] = f2bf(s4.z); tmp[3] = f2bf(s4.w);
        *(ushortx4*)(T + (size_t)(r0 + row) * RK + col4) = *(ushortx4*)tmp;

        // fused row norm: reduce ||T_row||^2 across the 32 lanes owning the row
        float ss = s4.x * s4.x + s4.y * s4.y + s4.z * s4.z + s4.w * s4.w;
        ss += __shfl_xor(ss, 1,  64);
        ss += __shfl_xor(ss, 2,  64);
        ss += __shfl_xor(ss, 4,  64);
        ss += __shfl_xor(ss, 8,  64);
        ss += __shfl_xor(ss, 16, 64);
        if ((t & 31) == 0) Nrm[r0 + row] = ss;
    }
}

// ---------- Kernel 2: D[b,i,j] = nI + nJ - 2 * (T_i . T_j), via MFMA ----------
// Grid (8 jt, 8 it, 8 b), 256 threads = 4 waves; 64x64 tile; wave w -> 16 i-rows.
// NO LDS, NO barriers: A/B fragments are contiguous dwordx4 reads from
// L2-resident T (1 MB); norms read per-lane from Nrm. ~8 blocks/CU occupancy.
__global__ __launch_bounds__(256) void dist_direct(
    const unsigned short* __restrict__ T, const float* __restrict__ Nrm,
    float* __restrict__ out)
{
    const int t    = threadIdx.x;
    const int w    = t >> 6;
    const int l    = t & 63;
    const int lm   = l & 15;
    const int quad = l >> 4;
    const int jt = blockIdx.x, it = blockIdx.y, b = blockIdx.z;
    const int i0 = it * 64, j0 = jt * 64;
    const unsigned short* Tb = T + (size_t)b * SEQ * RK;

    floatx4 acc[4];
    #pragma unroll
    for (int i = 0; i < 4; ++i) acc[i] = (floatx4){0.f, 0.f, 0.f, 0.f};

    const unsigned short* ai = Tb + (size_t)(i0 + w * 16 + lm) * RK + quad * 8;
    const unsigned short* bj = Tb + (size_t)(j0 + lm) * RK + quad * 8;

    #pragma unroll
    for (int s = 0; s < 4; ++s) {
        bf16x8 av = *(const bf16x8*)(ai + s * 32);
        #pragma unroll
        for (int nt = 0; nt < 4; ++nt) {
            bf16x8 bv = *(const bf16x8*)(bj + (size_t)nt * 16 * RK + s * 32);
            acc[nt] = __builtin_amdgcn_mfma_f32_16x16x32_bf16(av, bv, acc[nt], 0, 0, 0);
        }
    }

    const float* NrmB = Nrm + (size_t)b * SEQ;
    float niv[4];
    #pragma unroll
    for (int r = 0; r < 4; ++r) niv[r] = NrmB[i0 + w * 16 + quad * 4 + r];

    float* ob = out + ((size_t)b * SEQ + (i0 + w * 16)) * SEQ + j0;
    #pragma unroll
    for (int nt = 0; nt < 4; ++nt) {
        float njv = NrmB[j0 + nt * 16 + lm];
        #pragma unroll
        for (int r = 0; r < 4; ++r) {
            ob[(size_t)(quad * 4 + r) * SEQ + nt * 16 + lm] =
                niv[r] + njv - 2.f * acc[nt][r];
        }
    }
}

extern "C" void kernel_launch(void* const* d_in, const int* in_sizes, int n_in,
                              void* d_out, int out_size, void* d_ws, size_t ws_size,
                              hipStream_t stream) {
    const float* batch = (const float*)d_in[0];   // (8, 512, 1024) fp32
    const float* proj  = (const float*)d_in[1];   // (1024, 128) fp32
    float* out = (float*)d_out;                   // (8, 512, 512) fp32

    unsigned short* T   = (unsigned short*)d_ws;                      // 1 MB bf16
    float*          Nrm = (float*)((char*)d_ws + (1 << 20));          // 16 KB fp32

    proj_direct<<<256, 512, 0, stream>>>(batch, proj, T, Nrm);
    dist_direct<<<dim3(8, 8, 8), 256, 0, stream>>>(T, Nrm, out);
}

// Round 10
// 76.291 us; speedup vs baseline: 1.0312x; 1.0312x over previous
//
#include <hip/hip_runtime.h>

#define SEQ 512
#define MD  1024
#define RK  128

typedef __attribute__((ext_vector_type(8))) short  bf16x8;
typedef __attribute__((ext_vector_type(4))) float  floatx4;
typedef __attribute__((ext_vector_type(4))) unsigned int uint4v;
typedef __attribute__((ext_vector_type(4))) unsigned short ushortx4;

// RNE f32->bf16 -- keeps absmax at 2.0 (truncation measured at 6.0, too close
// to the 7.88 threshold; RNE was time-neutral -- cvt is not on the critical path)
__device__ inline unsigned short f2bf(float f) {
    union { float f; unsigned u; } v; v.f = f;
    unsigned r = v.u + 0x7fffu + ((v.u >> 16) & 1u);
    return (unsigned short)(r >> 16);
}

#define REDW 2112   // 16 * 132 floats per wave partial (proj reduce)

// ---------- Kernel 1: T = bf16(batch @ proj) + row norms, via MFMA ----------
// 256 blocks x 512 threads (8 waves). Block owns 16 rows; wave w owns a K-eighth.
// A-frags: fp32 dwordx4 from batch + RNE cvt. B-frags: 8 strided dword gathers
// from fp32 proj (512 KB, L2/L3-resident, shared by all blocks) -- no transpose
// kernel. One barrier before the conflict-free b128 cross-wave reduce.
__global__ __launch_bounds__(512, 2) void proj_direct(
    const float* __restrict__ batch, const float* __restrict__ proj,
    unsigned short* __restrict__ T, float* __restrict__ Nrm)
{
    __shared__ float Red[8 * REDW];   // 67.6 KB

    const int t    = threadIdx.x;
    const int w    = t >> 6;
    const int l    = t & 63;
    const int lm   = l & 15;
    const int quad = l >> 4;
    const int r0   = blockIdx.x * 16;

    floatx4 acc[8];
    #pragma unroll
    for (int i = 0; i < 8; ++i) acc[i] = (floatx4){0.f, 0.f, 0.f, 0.f};

    const float* arow = batch + (size_t)(r0 + lm) * MD + w * 128 + quad * 8;

    #pragma unroll
    for (int s = 0; s < 4; ++s) {
        // A fragment: lane holds A[m=lm][k = w*128 + s*32 + quad*8 + j]
        float4 a0 = *(const float4*)(arow + s * 32);
        float4 a1 = *(const float4*)(arow + s * 32 + 4);
        bf16x8 av;
        av[0] = (short)f2bf(a0.x); av[1] = (short)f2bf(a0.y);
        av[2] = (short)f2bf(a0.z); av[3] = (short)f2bf(a0.w);
        av[4] = (short)f2bf(a1.x); av[5] = (short)f2bf(a1.y);
        av[6] = (short)f2bf(a1.z); av[7] = (short)f2bf(a1.w);

        // B fragments: lane needs proj[k][n], n = nt*16+lm, k stride RK
        const float* bk = proj + (size_t)(w * 128 + s * 32 + quad * 8) * RK + lm;
        #pragma unroll
        for (int nt = 0; nt < 8; ++nt) {
            const float* bp = bk + nt * 16;
            bf16x8 bv;
            #pragma unroll
            for (int j = 0; j < 8; ++j)
                bv[j] = (short)f2bf(bp[(size_t)j * RK]);
            acc[nt] = __builtin_amdgcn_mfma_f32_16x16x32_bf16(av, bv, acc[nt], 0, 0, 0);
        }
    }

    // dump per-wave partials; row stride 132 -> 2-way bank alias only (free)
    #pragma unroll
    for (int nt = 0; nt < 8; ++nt) {
        #pragma unroll
        for (int r = 0; r < 4; ++r) {
            Red[w * REDW + (quad * 4 + r) * 132 + nt * 16 + lm] = acc[nt][r];
        }
    }
    __syncthreads();

    // conflict-free b128 reduce: thread -> (row = t>>5, col4 = (t&31)*4)
    {
        const int row  = t >> 5;
        const int col4 = (t & 31) * 4;
        float4 s4 = {0.f, 0.f, 0.f, 0.f};
        #pragma unroll
        for (int ww = 0; ww < 8; ++ww) {
            float4 p = *(const float4*)(Red + ww * REDW + row * 132 + col4);
            s4.x += p.x; s4.y += p.y; s4.z += p.z; s4.w += p.w;
        }
        unsigned short tmp[4];
        tmp[0] = f2bf(s4.x); tmp[1] = f2bf(s4.y);
        tmp[2] = f2bf(s4.z); tmp[3] = f2bf(s4.w);
        *(ushortx4*)(T + (size_t)(r0 + row) * RK + col4) = *(ushortx4*)tmp;

        // fused row norm: reduce ||T_row||^2 across the 32 lanes owning the row
        float ss = s4.x * s4.x + s4.y * s4.y + s4.z * s4.z + s4.w * s4.w;
        ss += __shfl_xor(ss, 1,  64);
        ss += __shfl_xor(ss, 2,  64);
        ss += __shfl_xor(ss, 4,  64);
        ss += __shfl_xor(ss, 8,  64);
        ss += __shfl_xor(ss, 16, 64);
        if ((t & 31) == 0) Nrm[r0 + row] = ss;
    }
}

// ---------- Kernel 2: D[b,i,j] = nI + nJ - 2 * (T_i . T_j), via MFMA ----------
// Grid (8 jt, 8 it, 8 b), 256 threads = 4 waves; 64x64 tile; wave w -> 16 i-rows.
#define LDB 136   // 128 + 8 bf16 pad: 16B rows, stride/16B odd -> 2-way alias only

__global__ __launch_bounds__(256) void dist_mfma(
    const unsigned short* __restrict__ T, const float* __restrict__ Nrm,
    float* __restrict__ out)
{
    __shared__ unsigned short Ti[64 * LDB];
    __shared__ unsigned short Tj[64 * LDB];
    __shared__ float nI[64], nJ[64];

    const int t    = threadIdx.x;
    const int w    = t >> 6;
    const int l    = t & 63;
    const int lm   = l & 15;
    const int quad = l >> 4;
    const int jt = blockIdx.x, it = blockIdx.y, b = blockIdx.z;
    const int i0 = it * 64, j0 = jt * 64;
    const unsigned short* Tb = T + (size_t)b * SEQ * RK;

    {   // stage both 64x128 bf16 tiles + norms
        int row = t >> 2, kq = (t & 3) * 32;
        const unsigned short* si = Tb + (size_t)(i0 + row) * RK + kq;
        const unsigned short* sj = Tb + (size_t)(j0 + row) * RK + kq;
        #pragma unroll
        for (int q = 0; q < 4; ++q) {
            *(uint4v*)(Ti + row * LDB + kq + q * 8) = *(const uint4v*)(si + q * 8);
            *(uint4v*)(Tj + row * LDB + kq + q * 8) = *(const uint4v*)(sj + q * 8);
        }
        if (t < 64)       nI[t]      = Nrm[(size_t)b * SEQ + i0 + t];
        else if (t < 128) nJ[t - 64] = Nrm[(size_t)b * SEQ + j0 + (t - 64)];
    }
    __syncthreads();

    floatx4 acc[4];
    #pragma unroll
    for (int i = 0; i < 4; ++i) acc[i] = (floatx4){0.f, 0.f, 0.f, 0.f};

    #pragma unroll
    for (int s = 0; s < 4; ++s) {
        bf16x8 av = *(const bf16x8*)(Ti + (w * 16 + lm) * LDB + s * 32 + quad * 8);
        #pragma unroll
        for (int nt = 0; nt < 4; ++nt) {
            bf16x8 bv = *(const bf16x8*)(Tj + (nt * 16 + lm) * LDB + s * 32 + quad * 8);
            acc[nt] = __builtin_amdgcn_mfma_f32_16x16x32_bf16(av, bv, acc[nt], 0, 0, 0);
        }
    }

    float niv[4];
    #pragma unroll
    for (int r = 0; r < 4; ++r) niv[r] = nI[w * 16 + quad * 4 + r];

    float* ob = out + ((size_t)b * SEQ + (i0 + w * 16)) * SEQ + j0;
    #pragma unroll
    for (int nt = 0; nt < 4; ++nt) {
        float njv = nJ[nt * 16 + lm];
        #pragma unroll
        for (int r = 0; r < 4; ++r) {
            ob[(size_t)(quad * 4 + r) * SEQ + nt * 16 + lm] =
                niv[r] + njv - 2.f * acc[nt][r];
        }
    }
}

extern "C" void kernel_launch(void* const* d_in, const int* in_sizes, int n_in,
                              void* d_out, int out_size, void* d_ws, size_t ws_size,
                              hipStream_t stream) {
    const float* batch = (const float*)d_in[0];   // (8, 512, 1024) fp32
    const float* proj  = (const float*)d_in[1];   // (1024, 128) fp32
    float* out = (float*)d_out;                   // (8, 512, 512) fp32

    unsigned short* T   = (unsigned short*)d_ws;                      // 1 MB bf16
    float*          Nrm = (float*)((char*)d_ws + (1 << 20));          // 16 KB fp32

    proj_direct<<<256, 512, 0, stream>>>(batch, proj, T, Nrm);
    dist_mfma<<<dim3(8, 8, 8), 256, 0, stream>>>(T, Nrm, out);
}